// Round 12
// baseline (454.564 us; speedup 1.0000x reference)
//
#include <hip/hip_runtime.h>
#include <hip/hip_bf16.h>

#define FEAT 128

typedef unsigned int uint32;
typedef unsigned short ushort16;
typedef __attribute__((ext_vector_type(8))) short short8;
typedef __attribute__((ext_vector_type(4))) float v4f;
typedef __attribute__((ext_vector_type(2))) float f32x2;

// ---- bf16 helpers (RNE round; bf16->f32 is exact shift) ---------------------
__device__ __forceinline__ ushort16 f2bf(float f) {
    uint32 u = __float_as_uint(f);
    u += 0x7fffu + ((u >> 16) & 1u);
    return (ushort16)(u >> 16);
}
__device__ __forceinline__ float bflo(uint32 u) { return __uint_as_float(u << 16); }
__device__ __forceinline__ float bfhi(uint32 u) { return __uint_as_float(u & 0xffff0000u); }
__device__ __forceinline__ f32x2 up2(uint32 u) { return (f32x2){bflo(u), bfhi(u)}; }

// ---------------- hydra: hist + W01=W0@W1 + zero(P) --------------------------
__global__ __launch_bounds__(256) void hydra_kernel(const int* __restrict__ col,
                                                    int* __restrict__ counts,
                                                    const float* __restrict__ W0,
                                                    const float* __restrict__ W1,
                                                    ushort16* __restrict__ W01t,
                                                    float* __restrict__ Pbuf,
                                                    int histBlocks, int E) {
    int b = blockIdx.x;
    int t = threadIdx.x;
    if (b < histBlocks) {
        int id = b * 256 + t;
        if (id * 4 + 3 < E) {
            int4 c4 = *(const int4*)(col + id * 4);
            atomicAdd(&counts[c4.x], 1);
            atomicAdd(&counts[c4.y], 1);
            atomicAdd(&counts[c4.z], 1);
            atomicAdd(&counts[c4.w], 1);
        } else {
            for (int e = id * 4; e < E; e++) atomicAdd(&counts[col[e]], 1);
        }
    } else if (b < histBlocks + 64) {
        __shared__ float sW0[2][FEAT];
        int wb = b - histBlocks;  // [0, 64)
        int lk = t >> 7;
        int ncol = t & 127;
        int k = wb * 2 + lk;
        sW0[lk][ncol] = W0[(size_t)k * FEAT + ncol];
        __syncthreads();
        float acc = 0.f;
#pragma unroll 4
        for (int j = 0; j < FEAT; j++)
            acc += sW0[lk][j] * W1[(size_t)j * FEAT + ncol];
        W01t[(size_t)ncol * FEAT + k] = f2bf(acc);  // [n][k], transposed for MFMA
    } else {
        int zb = b - histBlocks - 64;  // [0, 32): 512*128 floats
        float4 z = make_float4(0.f, 0.f, 0.f, 0.f);
        float* p = Pbuf + (size_t)zb * 2048 + t * 8;
        *(float4*)p = z;
        *(float4*)(p + 4) = z;
    }
}

// ---------------- scan step 1: per-1024-chunk sums ---------------------------
__global__ __launch_bounds__(256) void scan_part(const int* __restrict__ counts,
                                                 int* __restrict__ bsum, int n) {
    __shared__ int s[256];
    int base = blockIdx.x * 1024;
    int t = threadIdx.x;
    int v = 0;
#pragma unroll
    for (int i = 0; i < 4; i++) {
        int idx = base + t * 4 + i;
        if (idx < n) v += counts[idx];
    }
    s[t] = v;
    __syncthreads();
    for (int o = 128; o > 0; o >>= 1) {
        if (t < o) s[t] += s[t + o];
        __syncthreads();
    }
    if (t == 0) bsum[blockIdx.x] = s[0];
}

// ---------------- scan step 2 (merged): offsets + next[] + dinv --------------
__global__ __launch_bounds__(256) void scan_final(const int* __restrict__ counts,
                                                  const int* __restrict__ bsum,
                                                  int* __restrict__ off, int* __restrict__ nxt,
                                                  float* __restrict__ dinv, int n, int nb) {
    __shared__ int s[256];
    __shared__ int sb[128];
    int base = blockIdx.x * 1024;
    int t = threadIdx.x;
    if (t < nb) sb[t] = bsum[t];
    int c[4];
    int sum = 0;
#pragma unroll
    for (int i = 0; i < 4; i++) {
        int idx = base + t * 4 + i;
        c[i] = (idx < n) ? counts[idx] : 0;
        sum += c[i];
    }
    int v0 = sum;
    s[t] = sum;
    __syncthreads();
    for (int o = 1; o < 256; o <<= 1) {
        int v = (t >= o) ? s[t - o] : 0;
        __syncthreads();
        s[t] += v;
        __syncthreads();
    }
    int blockBase = 0;
    for (int j = 0; j < blockIdx.x; j++) blockBase += sb[j];
    int excl = s[t] - v0 + blockBase;
#pragma unroll
    for (int i = 0; i < 4; i++) {
        int idx = base + t * 4 + i;
        if (idx < n) {
            off[idx] = excl;
            nxt[idx] = excl;
            dinv[idx] = rsqrtf((float)(c[i] + 1));  // +1 = self loop
        }
        excl += c[i];
    }
    if (blockIdx.x == gridDim.x - 1 && t == 255) off[n] = excl;  // == E
}

// ---------------- CSR fill: 4B src records -----------------------------------
__global__ void fill_kernel(const int* __restrict__ row, const int* __restrict__ col,
                            int* __restrict__ nxt,
                            int* __restrict__ srcArr, int E) {
    int e = blockIdx.x * 256 + threadIdx.x;
    if (e < E) {
        int c = col[e], r = row[e];
        int p = atomicAdd(&nxt[c], 1);
        __builtin_nontemporal_store(r, &srcArr[p]);
    }
}

// ---------------- bf16 MFMA GEMM: halves = bf16(x @ W01), W transposed -------
// fp32 A (in-register convert). Output SPLIT into two half-feature tables
// [2][n][64] (R12: halves the gather's cache footprint). h = w&1 is already
// how waves partition columns -> zero-cost. OPERAND SWAP (verified R4):
// mfma(Wfrag, Afrag) -> lane holds 4 consecutive W-cols of node row l16.
__global__ __launch_bounds__(256) void gemm_mfma(const float* __restrict__ A,
                                                 const ushort16* __restrict__ Wt,
                                                 ushort16* __restrict__ Ch, int n) {
    const int t = threadIdx.x;
    const int w = t >> 6;
    const int lane = t & 63;
    const int quad = lane >> 4;
    const int l16 = lane & 15;
    const int h = w & 1;             // which 64-col half of W this wave owns
    const int colBase = h * 64;
    ushort16* halfC = Ch + (size_t)h * n * 64;  // half-table base

    short8 wf[4][4];
#pragma unroll
    for (int ct = 0; ct < 4; ct++) {
        const ushort16* wp = Wt + (size_t)(colBase + ct * 16 + l16) * FEAT + quad * 8;
#pragma unroll
        for (int ks = 0; ks < 4; ks++) wf[ct][ks] = *(const short8*)(wp + ks * 32);
    }

    const int nTiles = (n + 15) >> 4;
    const int tStride = gridDim.x * 2;
    int tile = blockIdx.x * 2 + (w >> 1);
    if (tile >= nTiles) return;

    auto loadA = [&](int tl, short8 (&a)[4]) {
        const int row = tl * 16 + l16;
        if (row < n) {
#pragma unroll
            for (int ks = 0; ks < 4; ks++) {
                const float* ap = A + (size_t)row * FEAT + quad * 8 + ks * 32;
                float4 f0 = *(const float4*)ap;
                float4 f1 = *(const float4*)(ap + 4);
                short8 v;
                v[0] = f2bf(f0.x); v[1] = f2bf(f0.y); v[2] = f2bf(f0.z); v[3] = f2bf(f0.w);
                v[4] = f2bf(f1.x); v[5] = f2bf(f1.y); v[6] = f2bf(f1.z); v[7] = f2bf(f1.w);
                a[ks] = v;
            }
        } else {
#pragma unroll
            for (int ks = 0; ks < 4; ks++) a[ks] = (short8)0;
        }
    };

    short8 aCur[4];
    loadA(tile, aCur);

    while (tile < nTiles) {
        const int nextTile = tile + tStride;
        short8 aNxt[4];
        if (nextTile < nTiles) loadA(nextTile, aNxt);

        v4f acc[4];
#pragma unroll
        for (int ct = 0; ct < 4; ct++) acc[ct] = (v4f)0.f;
#pragma unroll
        for (int ct = 0; ct < 4; ct++)
#pragma unroll
            for (int ks = 0; ks < 4; ks++)
                acc[ct] = __builtin_amdgcn_mfma_f32_16x16x32_bf16(wf[ct][ks], aCur[ks], acc[ct], 0, 0, 0);

        const int row = tile * 16 + l16;
        if (row < n) {
#pragma unroll
            for (int ct = 0; ct < 4; ct++) {
                uint2 o;
                o.x = (uint32)f2bf(acc[ct][0]) | ((uint32)f2bf(acc[ct][1]) << 16);
                o.y = (uint32)f2bf(acc[ct][2]) | ((uint32)f2bf(acc[ct][3]) << 16);
                *(uint2*)(halfC + (size_t)row * 64 + ct * 16 + quad * 4) = o;
            }
        }

        tile = nextTile;
#pragma unroll
        for (int ks = 0; ks < 4; ks++) aCur[ks] = aNxt[ks];
    }
}

// ---------------- gather-propagate over a HALF (64-feature) bf16 table -------
// H[c] = dinv[c]^2*T[c] + sum_e dinv[c]*dinv[src_e]*T[src_e], per half-table.
// R12: two sequential passes per propagation, each with a 12.8 MB footprint
// (vs 25.6) to raise the L2 hit rate — the full gather was pinned at ~48us by
// 124.7 MB of L2-miss traffic. 8 edge-groups x 8 lanes x 16B, unroll 2
// (same 2 KB outstanding bytes/wave as the full-row version).
__global__ __launch_bounds__(256) void gather_kernel(const int* __restrict__ off,
                                                     const int* __restrict__ srcArr,
                                                     const float* __restrict__ dinv,
                                                     const uint4* __restrict__ T,
                                                     uint4* __restrict__ O, int n,
                                                     int leaky) {
    int node = blockIdx.x * 4 + (threadIdx.x >> 6);
    if (node >= n) return;
    int lane = threadIdx.x & 63;
    int grp = lane >> 3;  // edge group 0..7
    int l8 = lane & 7;    // 16B chunk within 128B half-row
    float dc = dinv[node];

    f32x2 acc[4];
    if (grp == 0) {  // self-loop term
        uint4 v = T[(size_t)node * 8 + l8];
        f32x2 w0 = (f32x2){dc * dc, dc * dc};
        acc[0] = w0 * up2(v.x);
        acc[1] = w0 * up2(v.y);
        acc[2] = w0 * up2(v.z);
        acc[3] = w0 * up2(v.w);
    } else {
#pragma unroll
        for (int j = 0; j < 4; j++) acc[j] = (f32x2){0.f, 0.f};
    }

    int s = off[node], e = off[node + 1];
    int i = s + grp;
    for (; i + 8 < e; i += 16) {  // two edges per iteration, both loads in flight
        int r0 = srcArr[i];
        int r1 = srcArr[i + 8];
        uint4 u0 = T[(size_t)r0 * 8 + l8];
        uint4 u1 = T[(size_t)r1 * 8 + l8];
        float f0 = dc * dinv[r0];
        float f1 = dc * dinv[r1];
        f32x2 n0 = (f32x2){f0, f0};
        f32x2 n1 = (f32x2){f1, f1};
        acc[0] += n0 * up2(u0.x);
        acc[1] += n0 * up2(u0.y);
        acc[2] += n0 * up2(u0.z);
        acc[3] += n0 * up2(u0.w);
        acc[0] += n1 * up2(u1.x);
        acc[1] += n1 * up2(u1.y);
        acc[2] += n1 * up2(u1.z);
        acc[3] += n1 * up2(u1.w);
    }
    if (i < e) {
        int r0 = srcArr[i];
        uint4 u0 = T[(size_t)r0 * 8 + l8];
        float f0 = dc * dinv[r0];
        f32x2 n0 = (f32x2){f0, f0};
        acc[0] += n0 * up2(u0.x);
        acc[1] += n0 * up2(u0.y);
        acc[2] += n0 * up2(u0.z);
        acc[3] += n0 * up2(u0.w);
    }

    float b[8] = {acc[0].x, acc[0].y, acc[1].x, acc[1].y,
                  acc[2].x, acc[2].y, acc[3].x, acc[3].y};
    // combine the 8 groups (lane bits 3,4,5)
#pragma unroll
    for (int j = 0; j < 8; j++) {
        b[j] += __shfl_xor(b[j], 8);
        b[j] += __shfl_xor(b[j], 16);
        b[j] += __shfl_xor(b[j], 32);
    }

    if (grp == 0) {
        if (leaky) {
#pragma unroll
            for (int j = 0; j < 8; j++) b[j] = (b[j] >= 0.f) ? b[j] : 0.01f * b[j];
        }
        uint4 o;
        o.x = (uint32)f2bf(b[0]) | ((uint32)f2bf(b[1]) << 16);
        o.y = (uint32)f2bf(b[2]) | ((uint32)f2bf(b[3]) << 16);
        o.z = (uint32)f2bf(b[4]) | ((uint32)f2bf(b[5]) << 16);
        o.w = (uint32)f2bf(b[6]) | ((uint32)f2bf(b[7]) << 16);
        O[(size_t)node * 8 + l8] = o;
    }
}

// ---------------- pool: P[g] += G3[i] (sorted batch); input = half-tables ----
__global__ __launch_bounds__(128) void pool_kernel(const ushort16* __restrict__ H,
                                                   const int* __restrict__ batch,
                                                   float* __restrict__ P, int n) {
    int t = threadIdx.x;  // feature
    const ushort16* Hh = H + (size_t)(t >> 6) * n * 64;  // which half-table
    int f = t & 63;
    int i0 = blockIdx.x * 64;
    if (i0 >= n) return;
    int i1 = min(i0 + 64, n);
    float acc = 0.f;
    int g = batch[i0];
    for (int i = i0; i < i1; i++) {
        int b = batch[i];
        if (b != g) {
            atomicAdd(&P[(size_t)g * FEAT + t], acc);
            acc = 0.f;
            g = b;
        }
        uint32 u = (uint32)(unsigned short)Hh[(size_t)i * 64 + f];
        acc += __uint_as_float(u << 16);
    }
    atomicAdd(&P[(size_t)g * FEAT + t], acc);
}

// ---------------- final tiny GEMM: out[g] = P[g] @ W2 (fp32) -----------------
__global__ __launch_bounds__(128) void pgemm_kernel(const float* __restrict__ P,
                                                    const float* __restrict__ W2,
                                                    float* __restrict__ out) {
    __shared__ float sP[FEAT];
    const int g = blockIdx.x;
    const int t = threadIdx.x;
    sP[t] = P[(size_t)g * FEAT + t];
    __syncthreads();
    float o = 0.f;
#pragma unroll 4
    for (int k = 0; k < FEAT; k++) o += sP[k] * W2[(size_t)k * FEAT + t];
    out[(size_t)g * FEAT + t] = o;
}

extern "C" void kernel_launch(void* const* d_in, const int* in_sizes, int n_in,
                              void* d_out, int out_size, void* d_ws, size_t ws_size,
                              hipStream_t stream) {
    const float* x = (const float*)d_in[0];
    const int* ei = (const int*)d_in[1];
    const int* batch = (const int*)d_in[2];
    const float* W0 = (const float*)d_in[3];
    const float* W1 = (const float*)d_in[4];
    const float* W2 = (const float*)d_in[5];
    float* out = (float*)d_out;

    const int N = in_sizes[0] / FEAT;  // 100000
    const int E = in_sizes[1] / 2;     // 640000
    const int G = out_size / FEAT;     // 512

    const int* rowI = ei;
    const int* colI = ei + E;

    char* ws = (char*)d_ws;
    auto take = [&](size_t bytes) {
        char* p = ws;
        ws += (bytes + 15) & ~(size_t)15;
        return p;
    };
    int* counts    = (int*)take((size_t)N * 4);
    int* off       = (int*)take((size_t)(N + 1) * 4);
    int* nxt       = (int*)take((size_t)N * 4);
    float* dinv    = (float*)take((size_t)N * 4);
    int* bsum      = (int*)take(128 * 4);
    int* srcArr    = (int*)take((size_t)E * 4);
    ushort16* W01t = (ushort16*)take((size_t)16384 * 2);
    float* Pbuf    = (float*)take((size_t)G * FEAT * 4);
    ushort16* bufA = (ushort16*)take((size_t)N * FEAT * 2);  // [2][N][64]
    ushort16* bufB = (ushort16*)take((size_t)N * FEAT * 2);  // [2][N][64]

    const int nb = (N + 1023) / 1024;  // 98
    const int eb = (E + 255) / 256;

    // ---- zero counts, then pre-work (hist + W01 + zero P) ----
    hipMemsetAsync(counts, 0, (size_t)N * 4, stream);
    const int histBlocks = (E + 1023) / 1024;
    hydra_kernel<<<histBlocks + 64 + 32, 256, 0, stream>>>(
        colI, counts, W0, W1, W01t, Pbuf, histBlocks, E);

    // ---- CSR build (2-kernel scan) ----
    scan_part<<<nb, 256, 0, stream>>>(counts, bsum, N);
    scan_final<<<nb, 256, 0, stream>>>(counts, bsum, off, nxt, dinv, N, nb);
    fill_kernel<<<eb, 256, 0, stream>>>(rowI, colI, nxt, srcArr, E);

    const int gatBlocks = (N + 3) / 4;
    uint4* A0 = (uint4*)bufA;
    uint4* A1 = (uint4*)(bufA + (size_t)N * 64);
    uint4* B0 = (uint4*)bufB;
    uint4* B1 = (uint4*)(bufB + (size_t)N * 64);

    // ---- Y = x@W01 (fp32 x read once; output split into half-tables) ----
    gemm_mfma<<<1024, 256, 0, stream>>>(x, W01t, bufA, N);
    // ---- H3 = leaky(A A Y): each propagation = 2 half-feature passes ----
    gather_kernel<<<gatBlocks, 256, 0, stream>>>(off, srcArr, dinv, A0, B0, N, 0);
    gather_kernel<<<gatBlocks, 256, 0, stream>>>(off, srcArr, dinv, A1, B1, N, 0);
    gather_kernel<<<gatBlocks, 256, 0, stream>>>(off, srcArr, dinv, B0, A0, N, 1);
    gather_kernel<<<gatBlocks, 256, 0, stream>>>(off, srcArr, dinv, B1, A1, N, 1);
    // ---- G3 = A H3 ----
    gather_kernel<<<gatBlocks, 256, 0, stream>>>(off, srcArr, dinv, A0, B0, N, 0);
    gather_kernel<<<gatBlocks, 256, 0, stream>>>(off, srcArr, dinv, A1, B1, N, 0);
    // ---- out = pool(G3) @ W2 ----
    pool_kernel<<<(N + 63) / 64, 128, 0, stream>>>(bufB, batch, Pbuf, N);
    pgemm_kernel<<<G, 128, 0, stream>>>(Pbuf, W2, out);
}

// Round 13
// 340.458 us; speedup vs baseline: 1.3352x; 1.3352x over previous
//
#include <hip/hip_runtime.h>
#include <hip/hip_bf16.h>

#define FEAT 128

typedef unsigned int uint32;
typedef unsigned short ushort16;
typedef __attribute__((ext_vector_type(8))) short short8;
typedef __attribute__((ext_vector_type(4))) float v4f;
typedef __attribute__((ext_vector_type(2))) float f32x2;

// ---- bf16 helpers (RNE round; bf16->f32 is exact shift) ---------------------
__device__ __forceinline__ ushort16 f2bf(float f) {
    uint32 u = __float_as_uint(f);
    u += 0x7fffu + ((u >> 16) & 1u);
    return (ushort16)(u >> 16);
}
__device__ __forceinline__ float bflo(uint32 u) { return __uint_as_float(u << 16); }
__device__ __forceinline__ float bfhi(uint32 u) { return __uint_as_float(u & 0xffff0000u); }
__device__ __forceinline__ f32x2 up2(uint32 u) { return (f32x2){bflo(u), bfhi(u)}; }

// ---------------- hydra: hist + W01=W0@W1 + zero(P) --------------------------
__global__ __launch_bounds__(256) void hydra_kernel(const int* __restrict__ col,
                                                    int* __restrict__ counts,
                                                    const float* __restrict__ W0,
                                                    const float* __restrict__ W1,
                                                    ushort16* __restrict__ W01t,
                                                    float* __restrict__ Pbuf,
                                                    int histBlocks, int E) {
    int b = blockIdx.x;
    int t = threadIdx.x;
    if (b < histBlocks) {
        int id = b * 256 + t;
        if (id * 4 + 3 < E) {
            int4 c4 = *(const int4*)(col + id * 4);
            atomicAdd(&counts[c4.x], 1);
            atomicAdd(&counts[c4.y], 1);
            atomicAdd(&counts[c4.z], 1);
            atomicAdd(&counts[c4.w], 1);
        } else {
            for (int e = id * 4; e < E; e++) atomicAdd(&counts[col[e]], 1);
        }
    } else if (b < histBlocks + 64) {
        __shared__ float sW0[2][FEAT];
        int wb = b - histBlocks;  // [0, 64)
        int lk = t >> 7;
        int ncol = t & 127;
        int k = wb * 2 + lk;
        sW0[lk][ncol] = W0[(size_t)k * FEAT + ncol];
        __syncthreads();
        float acc = 0.f;
#pragma unroll 4
        for (int j = 0; j < FEAT; j++)
            acc += sW0[lk][j] * W1[(size_t)j * FEAT + ncol];
        W01t[(size_t)ncol * FEAT + k] = f2bf(acc);  // [n][k], transposed for MFMA
    } else {
        int zb = b - histBlocks - 64;  // [0, 32): 512*128 floats
        float4 z = make_float4(0.f, 0.f, 0.f, 0.f);
        float* p = Pbuf + (size_t)zb * 2048 + t * 8;
        *(float4*)p = z;
        *(float4*)(p + 4) = z;
    }
}

// ---------------- scan step 1: per-1024-chunk sums ---------------------------
__global__ __launch_bounds__(256) void scan_part(const int* __restrict__ counts,
                                                 int* __restrict__ bsum, int n) {
    __shared__ int s[256];
    int base = blockIdx.x * 1024;
    int t = threadIdx.x;
    int v = 0;
#pragma unroll
    for (int i = 0; i < 4; i++) {
        int idx = base + t * 4 + i;
        if (idx < n) v += counts[idx];
    }
    s[t] = v;
    __syncthreads();
    for (int o = 128; o > 0; o >>= 1) {
        if (t < o) s[t] += s[t + o];
        __syncthreads();
    }
    if (t == 0) bsum[blockIdx.x] = s[0];
}

// ---------------- scan step 2 (merged): offsets + next[] + dinv --------------
__global__ __launch_bounds__(256) void scan_final(const int* __restrict__ counts,
                                                  const int* __restrict__ bsum,
                                                  int* __restrict__ off, int* __restrict__ nxt,
                                                  float* __restrict__ dinv, int n, int nb) {
    __shared__ int s[256];
    __shared__ int sb[128];
    int base = blockIdx.x * 1024;
    int t = threadIdx.x;
    if (t < nb) sb[t] = bsum[t];
    int c[4];
    int sum = 0;
#pragma unroll
    for (int i = 0; i < 4; i++) {
        int idx = base + t * 4 + i;
        c[i] = (idx < n) ? counts[idx] : 0;
        sum += c[i];
    }
    int v0 = sum;
    s[t] = sum;
    __syncthreads();
    for (int o = 1; o < 256; o <<= 1) {
        int v = (t >= o) ? s[t - o] : 0;
        __syncthreads();
        s[t] += v;
        __syncthreads();
    }
    int blockBase = 0;
    for (int j = 0; j < blockIdx.x; j++) blockBase += sb[j];
    int excl = s[t] - v0 + blockBase;
#pragma unroll
    for (int i = 0; i < 4; i++) {
        int idx = base + t * 4 + i;
        if (idx < n) {
            off[idx] = excl;
            nxt[idx] = excl;
            dinv[idx] = rsqrtf((float)(c[i] + 1));  // +1 = self loop
        }
        excl += c[i];
    }
    if (blockIdx.x == gridDim.x - 1 && t == 255) off[n] = excl;  // == E
}

// ---------------- FUSED gemm + fill ------------------------------------------
// fill (latency-bound: 640K scattered atomic+store round-trips, 0.3% VALU,
// ~47us alone) and gemm (~45us alone) are independent; interleaved block
// roles (b%7<2 -> gemm = 1024 blocks, else fill = 2560 slots) co-schedule
// them so fill's latency hides behind gemm's MFMA. Serial cost was ~92us.
// GEMM: bf16(x @ W01), fp32 A converted in-register. Half-W-per-wave
// register-resident (R6). OPERAND SWAP (verified R4): mfma(Wfrag, Afrag) ->
// lane holds 4 consecutive W-cols of node row l16 -> direct 8B stores.
__global__ __launch_bounds__(256) void gemmfill_kernel(const float* __restrict__ A,
                                                       const ushort16* __restrict__ Wt,
                                                       ushort16* __restrict__ Ch, int n,
                                                       const int* __restrict__ row,
                                                       const int* __restrict__ col,
                                                       int* __restrict__ nxt,
                                                       int* __restrict__ srcArr, int E) {
    const int b = blockIdx.x;
    const int r7 = b % 7;
    const int g7 = b / 7;
    const int t = threadIdx.x;

    if (r7 >= 2) {
        // ---- fill role: 5/7 of blocks -> fill block id in [0, 2560) ----
        int fb = g7 * 5 + (r7 - 2);
        int e = fb * 256 + t;
        if (e < E) {
            int c = col[e], r = row[e];
            int p = atomicAdd(&nxt[c], 1);
            __builtin_nontemporal_store(r, &srcArr[p]);
        }
        return;
    }

    // ---- gemm role: 2/7 of blocks -> gemm block id gb in [0, 1024) ----
    const int gb = g7 * 2 + r7;
    const int GEMM_BLOCKS = 1024;
    const int w = t >> 6;
    const int lane = t & 63;
    const int quad = lane >> 4;
    const int l16 = lane & 15;
    const int colBase = (w & 1) * 64;

    short8 wf[4][4];
#pragma unroll
    for (int ct = 0; ct < 4; ct++) {
        const ushort16* wp = Wt + (size_t)(colBase + ct * 16 + l16) * FEAT + quad * 8;
#pragma unroll
        for (int ks = 0; ks < 4; ks++) wf[ct][ks] = *(const short8*)(wp + ks * 32);
    }

    const int nTiles = (n + 15) >> 4;
    const int tStride = GEMM_BLOCKS * 2;
    int tile = gb * 2 + (w >> 1);
    if (tile >= nTiles) return;

    auto loadA = [&](int tl, short8 (&a)[4]) {
        const int rowi = tl * 16 + l16;
        if (rowi < n) {
#pragma unroll
            for (int ks = 0; ks < 4; ks++) {
                const float* ap = A + (size_t)rowi * FEAT + quad * 8 + ks * 32;
                float4 f0 = *(const float4*)ap;
                float4 f1 = *(const float4*)(ap + 4);
                short8 v;
                v[0] = f2bf(f0.x); v[1] = f2bf(f0.y); v[2] = f2bf(f0.z); v[3] = f2bf(f0.w);
                v[4] = f2bf(f1.x); v[5] = f2bf(f1.y); v[6] = f2bf(f1.z); v[7] = f2bf(f1.w);
                a[ks] = v;
            }
        } else {
#pragma unroll
            for (int ks = 0; ks < 4; ks++) a[ks] = (short8)0;
        }
    };

    short8 aCur[4];
    loadA(tile, aCur);

    while (tile < nTiles) {
        const int nextTile = tile + tStride;
        short8 aNxt[4];
        if (nextTile < nTiles) loadA(nextTile, aNxt);

        v4f acc[4];
#pragma unroll
        for (int ct = 0; ct < 4; ct++) acc[ct] = (v4f)0.f;
#pragma unroll
        for (int ct = 0; ct < 4; ct++)
#pragma unroll
            for (int ks = 0; ks < 4; ks++)
                acc[ct] = __builtin_amdgcn_mfma_f32_16x16x32_bf16(wf[ct][ks], aCur[ks], acc[ct], 0, 0, 0);

        const int rowi = tile * 16 + l16;
        if (rowi < n) {
#pragma unroll
            for (int ct = 0; ct < 4; ct++) {
                uint2 o;
                o.x = (uint32)f2bf(acc[ct][0]) | ((uint32)f2bf(acc[ct][1]) << 16);
                o.y = (uint32)f2bf(acc[ct][2]) | ((uint32)f2bf(acc[ct][3]) << 16);
                *(uint2*)(Ch + (size_t)rowi * FEAT + colBase + ct * 16 + quad * 4) = o;
            }
        }

        tile = nextTile;
#pragma unroll
        for (int ks = 0; ks < 4; ks++) aCur[ks] = aNxt[ks];
    }
}

// ---------------- gather-propagate over bf16 table (R11 structure) -----------
// H[c] = dinv[c]^2*T[c] + sum_e dinv[c]*dinv[src_e]*T[src_e].
// 4 edge-groups x 16 lanes x 16B, unroll-2. Measured floor ~48us (L2-miss
// traffic at L3 random-access rate; R12's half-table split REGRESSED).
__global__ __launch_bounds__(256) void gather_kernel(const int* __restrict__ off,
                                                     const int* __restrict__ srcArr,
                                                     const float* __restrict__ dinv,
                                                     const ushort16* __restrict__ XWh,
                                                     ushort16* __restrict__ Hh, int n,
                                                     int leaky) {
    int node = blockIdx.x * 4 + (threadIdx.x >> 6);
    if (node >= n) return;
    int lane = threadIdx.x & 63;
    int grp = lane >> 4;
    int l16 = lane & 15;
    float dc = dinv[node];
    const uint4* table = (const uint4*)XWh;

    f32x2 acc[4];
    if (grp == 0) {  // self-loop term
        uint4 v = table[(size_t)node * 16 + l16];
        f32x2 w0 = (f32x2){dc * dc, dc * dc};
        acc[0] = w0 * up2(v.x);
        acc[1] = w0 * up2(v.y);
        acc[2] = w0 * up2(v.z);
        acc[3] = w0 * up2(v.w);
    } else {
#pragma unroll
        for (int j = 0; j < 4; j++) acc[j] = (f32x2){0.f, 0.f};
    }

    int s = off[node], e = off[node + 1];
    int i = s + grp;
    for (; i + 4 < e; i += 8) {
        int r0 = srcArr[i];
        int r1 = srcArr[i + 4];
        uint4 u0 = table[(size_t)r0 * 16 + l16];
        uint4 u1 = table[(size_t)r1 * 16 + l16];
        float f0 = dc * dinv[r0];
        float f1 = dc * dinv[r1];
        f32x2 n0 = (f32x2){f0, f0};
        f32x2 n1 = (f32x2){f1, f1};
        acc[0] += n0 * up2(u0.x);
        acc[1] += n0 * up2(u0.y);
        acc[2] += n0 * up2(u0.z);
        acc[3] += n0 * up2(u0.w);
        acc[0] += n1 * up2(u1.x);
        acc[1] += n1 * up2(u1.y);
        acc[2] += n1 * up2(u1.z);
        acc[3] += n1 * up2(u1.w);
    }
    if (i < e) {
        int r0 = srcArr[i];
        uint4 u0 = table[(size_t)r0 * 16 + l16];
        float f0 = dc * dinv[r0];
        f32x2 n0 = (f32x2){f0, f0};
        acc[0] += n0 * up2(u0.x);
        acc[1] += n0 * up2(u0.y);
        acc[2] += n0 * up2(u0.z);
        acc[3] += n0 * up2(u0.w);
    }

    float b[8] = {acc[0].x, acc[0].y, acc[1].x, acc[1].y,
                  acc[2].x, acc[2].y, acc[3].x, acc[3].y};
#pragma unroll
    for (int j = 0; j < 8; j++) {
        b[j] += __shfl_xor(b[j], 16);
        b[j] += __shfl_xor(b[j], 32);
    }

    if (grp == 0) {
        if (leaky) {
#pragma unroll
            for (int j = 0; j < 8; j++) b[j] = (b[j] >= 0.f) ? b[j] : 0.01f * b[j];
        }
        uint4 o;
        o.x = (uint32)f2bf(b[0]) | ((uint32)f2bf(b[1]) << 16);
        o.y = (uint32)f2bf(b[2]) | ((uint32)f2bf(b[3]) << 16);
        o.z = (uint32)f2bf(b[4]) | ((uint32)f2bf(b[5]) << 16);
        o.w = (uint32)f2bf(b[6]) | ((uint32)f2bf(b[7]) << 16);
        *(uint4*)(Hh + (size_t)node * FEAT + l16 * 8) = o;
    }
}

// ---------------- pool: P[g] += G3[i] for batch[i]==g (sorted) ---------------
__global__ __launch_bounds__(128) void pool_kernel(const ushort16* __restrict__ H,
                                                   const int* __restrict__ batch,
                                                   float* __restrict__ P, int n) {
    int t = threadIdx.x;  // feature
    int i0 = blockIdx.x * 64;
    if (i0 >= n) return;
    int i1 = min(i0 + 64, n);
    float acc = 0.f;
    int g = batch[i0];
    for (int i = i0; i < i1; i++) {
        int b = batch[i];
        if (b != g) {
            atomicAdd(&P[(size_t)g * FEAT + t], acc);
            acc = 0.f;
            g = b;
        }
        uint32 u = (uint32)(unsigned short)H[(size_t)i * FEAT + t];
        acc += __uint_as_float(u << 16);
    }
    atomicAdd(&P[(size_t)g * FEAT + t], acc);
}

// ---------------- final tiny GEMM: out[g] = P[g] @ W2 (fp32) -----------------
__global__ __launch_bounds__(128) void pgemm_kernel(const float* __restrict__ P,
                                                    const float* __restrict__ W2,
                                                    float* __restrict__ out) {
    __shared__ float sP[FEAT];
    const int g = blockIdx.x;
    const int t = threadIdx.x;
    sP[t] = P[(size_t)g * FEAT + t];
    __syncthreads();
    float o = 0.f;
#pragma unroll 4
    for (int k = 0; k < FEAT; k++) o += sP[k] * W2[(size_t)k * FEAT + t];
    out[(size_t)g * FEAT + t] = o;
}

extern "C" void kernel_launch(void* const* d_in, const int* in_sizes, int n_in,
                              void* d_out, int out_size, void* d_ws, size_t ws_size,
                              hipStream_t stream) {
    const float* x = (const float*)d_in[0];
    const int* ei = (const int*)d_in[1];
    const int* batch = (const int*)d_in[2];
    const float* W0 = (const float*)d_in[3];
    const float* W1 = (const float*)d_in[4];
    const float* W2 = (const float*)d_in[5];
    float* out = (float*)d_out;

    const int N = in_sizes[0] / FEAT;  // 100000
    const int E = in_sizes[1] / 2;     // 640000
    const int G = out_size / FEAT;     // 512

    const int* rowI = ei;
    const int* colI = ei + E;

    char* ws = (char*)d_ws;
    auto take = [&](size_t bytes) {
        char* p = ws;
        ws += (bytes + 15) & ~(size_t)15;
        return p;
    };
    int* counts    = (int*)take((size_t)N * 4);
    int* off       = (int*)take((size_t)(N + 1) * 4);
    int* nxt       = (int*)take((size_t)N * 4);
    float* dinv    = (float*)take((size_t)N * 4);
    int* bsum      = (int*)take(128 * 4);
    int* srcArr    = (int*)take((size_t)E * 4);
    ushort16* W01t = (ushort16*)take((size_t)16384 * 2);
    float* Pbuf    = (float*)take((size_t)G * FEAT * 4);
    ushort16* bufA = (ushort16*)take((size_t)N * FEAT * 2);
    ushort16* bufB = (ushort16*)take((size_t)N * FEAT * 2);

    const int nb = (N + 1023) / 1024;  // 98

    // ---- zero counts, then pre-work (hist + W01 + zero P) ----
    hipMemsetAsync(counts, 0, (size_t)N * 4, stream);
    const int histBlocks = (E + 1023) / 1024;
    hydra_kernel<<<histBlocks + 64 + 32, 256, 0, stream>>>(
        colI, counts, W0, W1, W01t, Pbuf, histBlocks, E);

    // ---- CSR build (2-kernel scan) ----
    scan_part<<<nb, 256, 0, stream>>>(counts, bsum, N);
    scan_final<<<nb, 256, 0, stream>>>(counts, bsum, off, nxt, dinv, N, nb);

    // ---- fused: Y = x@W01 (1024 blocks) || CSR fill (2560 slots) ----
    gemmfill_kernel<<<512 * 7, 256, 0, stream>>>(x, W01t, bufA, N,
                                                 rowI, colI, nxt, srcArr, E);

    const int gatBlocks = (N + 3) / 4;
    // ---- H3 = leaky(A A Y) ----
    gather_kernel<<<gatBlocks, 256, 0, stream>>>(off, srcArr, dinv, bufA, bufB, N, 0);
    gather_kernel<<<gatBlocks, 256, 0, stream>>>(off, srcArr, dinv, bufB, bufA, N, 1);
    // ---- G3 = A H3 ----
    gather_kernel<<<gatBlocks, 256, 0, stream>>>(off, srcArr, dinv, bufA, bufB, N, 0);
    // ---- out = pool(G3) @ W2 ----
    pool_kernel<<<(N + 63) / 64, 128, 0, stream>>>(bufB, batch, Pbuf, N);
    pgemm_kernel<<<G, 128, 0, stream>>>(Pbuf, W2, out);
}

// Round 14
// 332.093 us; speedup vs baseline: 1.3688x; 1.0252x over previous
//
#include <hip/hip_runtime.h>
#include <hip/hip_bf16.h>

#define FEAT 128

typedef unsigned int uint32;
typedef unsigned short ushort16;
typedef __attribute__((ext_vector_type(8))) short short8;
typedef __attribute__((ext_vector_type(4))) float v4f;
typedef __attribute__((ext_vector_type(2))) float f32x2;

// ---- bf16 helpers (RNE round; bf16->f32 is exact shift) ---------------------
__device__ __forceinline__ ushort16 f2bf(float f) {
    uint32 u = __float_as_uint(f);
    u += 0x7fffu + ((u >> 16) & 1u);
    return (ushort16)(u >> 16);
}
__device__ __forceinline__ float bflo(uint32 u) { return __uint_as_float(u << 16); }
__device__ __forceinline__ float bfhi(uint32 u) { return __uint_as_float(u & 0xffff0000u); }
__device__ __forceinline__ f32x2 up2(uint32 u) { return (f32x2){bflo(u), bfhi(u)}; }

// ---------------- shared gemm body: half-W-per-wave register-resident --------
// (R6 design, frozen). OPERAND SWAP (verified R4): mfma(Wfrag, Afrag) ->
// lane holds 4 consecutive W-cols of node row l16 -> direct 8B stores.
// Processes tiles [tile0, tile1) with the given wave-pair id and stride.
__device__ __forceinline__ void gemm_body(const float* __restrict__ A,
                                          const ushort16* __restrict__ Wt,
                                          ushort16* __restrict__ Ch, int n,
                                          int pairId, int pairStride,
                                          int tile0, int tile1, int t) {
    const int w = t >> 6;
    const int lane = t & 63;
    const int quad = lane >> 4;
    const int l16 = lane & 15;
    const int colBase = (w & 1) * 64;

    short8 wf[4][4];
#pragma unroll
    for (int ct = 0; ct < 4; ct++) {
        const ushort16* wp = Wt + (size_t)(colBase + ct * 16 + l16) * FEAT + quad * 8;
#pragma unroll
        for (int ks = 0; ks < 4; ks++) wf[ct][ks] = *(const short8*)(wp + ks * 32);
    }

    int tile = tile0 + pairId;
    if (tile >= tile1) return;

    auto loadA = [&](int tl, short8 (&a)[4]) {
        const int rowi = tl * 16 + l16;
        if (rowi < n) {
#pragma unroll
            for (int ks = 0; ks < 4; ks++) {
                const float* ap = A + (size_t)rowi * FEAT + quad * 8 + ks * 32;
                float4 f0 = *(const float4*)ap;
                float4 f1 = *(const float4*)(ap + 4);
                short8 v;
                v[0] = f2bf(f0.x); v[1] = f2bf(f0.y); v[2] = f2bf(f0.z); v[3] = f2bf(f0.w);
                v[4] = f2bf(f1.x); v[5] = f2bf(f1.y); v[6] = f2bf(f1.z); v[7] = f2bf(f1.w);
                a[ks] = v;
            }
        } else {
#pragma unroll
            for (int ks = 0; ks < 4; ks++) a[ks] = (short8)0;
        }
    };

    short8 aCur[4];
    loadA(tile, aCur);

    while (tile < tile1) {
        const int nextTile = tile + pairStride;
        short8 aNxt[4];
        if (nextTile < tile1) loadA(nextTile, aNxt);

        v4f acc[4];
#pragma unroll
        for (int ct = 0; ct < 4; ct++) acc[ct] = (v4f)0.f;
#pragma unroll
        for (int ct = 0; ct < 4; ct++)
#pragma unroll
            for (int ks = 0; ks < 4; ks++)
                acc[ct] = __builtin_amdgcn_mfma_f32_16x16x32_bf16(wf[ct][ks], aCur[ks], acc[ct], 0, 0, 0);

        const int rowi = tile * 16 + l16;
        if (rowi < n) {
#pragma unroll
            for (int ct = 0; ct < 4; ct++) {
                uint2 o;
                o.x = (uint32)f2bf(acc[ct][0]) | ((uint32)f2bf(acc[ct][1]) << 16);
                o.y = (uint32)f2bf(acc[ct][2]) | ((uint32)f2bf(acc[ct][3]) << 16);
                *(uint2*)(Ch + (size_t)rowi * FEAT + colBase + ct * 16 + quad * 4) = o;
            }
        }

        tile = nextTile;
#pragma unroll
        for (int ks = 0; ks < 4; ks++) aCur[ks] = aNxt[ks];
    }
}

// ---------------- pre: zero counts + W01=W0@W1 + zero(P) ---------------------
// blocks [0,100): zero counts; [100,164): W01t; [164,196): zero Pbuf
__global__ __launch_bounds__(256) void pre_kernel(int* __restrict__ counts, int n,
                                                  const float* __restrict__ W0,
                                                  const float* __restrict__ W1,
                                                  ushort16* __restrict__ W01t,
                                                  float* __restrict__ Pbuf) {
    int b = blockIdx.x;
    int t = threadIdx.x;
    if (b < 100) {
        int idx = (b * 256 + t) * 4;
        if (idx + 3 < n) {
            *(int4*)(counts + idx) = make_int4(0, 0, 0, 0);
        } else {
            for (int i = idx; i < n; i++) counts[i] = 0;
        }
    } else if (b < 164) {
        __shared__ float sW0[2][FEAT];
        int wb = b - 100;  // [0, 64)
        int lk = t >> 7;
        int ncol = t & 127;
        int k = wb * 2 + lk;
        sW0[lk][ncol] = W0[(size_t)k * FEAT + ncol];
        __syncthreads();
        float acc = 0.f;
#pragma unroll 4
        for (int j = 0; j < FEAT; j++)
            acc += sW0[lk][j] * W1[(size_t)j * FEAT + ncol];
        W01t[(size_t)ncol * FEAT + k] = f2bf(acc);  // [n][k], transposed for MFMA
    } else {
        int zb = b - 164;  // [0, 32): 512*128 floats
        float4 z = make_float4(0.f, 0.f, 0.f, 0.f);
        float* p = Pbuf + (size_t)zb * 2048 + t * 8;
        *(float4*)p = z;
        *(float4*)(p + 4) = z;
    }
}

// ---------------- FUSED hist + gemm-half-A -----------------------------------
// hist: 2.56M random atomics = pure latency; gemmA (tiles [0,3125), 512
// blocks) hides behind it. Interleave b%9: r<4 -> gemm, else hist.
__global__ __launch_bounds__(256) void histgemmA_kernel(const int* __restrict__ col,
                                                        int* __restrict__ counts, int E,
                                                        const float* __restrict__ A,
                                                        const ushort16* __restrict__ Wt,
                                                        ushort16* __restrict__ Ch, int n) {
    const int b = blockIdx.x;
    const int r9 = b % 9;
    const int g9 = b / 9;
    const int t = threadIdx.x;
    if (r9 >= 4) {
        // hist role: 5/9 -> hist block id in [0, 640)
        int hb = g9 * 5 + (r9 - 4);
        int id = hb * 256 + t;
        if (id * 4 + 3 < E) {
            int4 c4 = *(const int4*)(col + id * 4);
            atomicAdd(&counts[c4.x], 1);
            atomicAdd(&counts[c4.y], 1);
            atomicAdd(&counts[c4.z], 1);
            atomicAdd(&counts[c4.w], 1);
        } else {
            for (int e = id * 4; e < E; e++) atomicAdd(&counts[col[e]], 1);
        }
        return;
    }
    // gemm role: 4/9 -> gemm block id in [0, 512); 1024 wave-pairs, stride 1024
    int gb = g9 * 4 + r9;
    gemm_body(A, Wt, Ch, n, gb * 2 + ((t >> 6) >> 1), 1024, 0, 3125, t);
}

// ---------------- scan step 1: per-1024-chunk sums ---------------------------
__global__ __launch_bounds__(256) void scan_part(const int* __restrict__ counts,
                                                 int* __restrict__ bsum, int n) {
    __shared__ int s[256];
    int base = blockIdx.x * 1024;
    int t = threadIdx.x;
    int v = 0;
#pragma unroll
    for (int i = 0; i < 4; i++) {
        int idx = base + t * 4 + i;
        if (idx < n) v += counts[idx];
    }
    s[t] = v;
    __syncthreads();
    for (int o = 128; o > 0; o >>= 1) {
        if (t < o) s[t] += s[t + o];
        __syncthreads();
    }
    if (t == 0) bsum[blockIdx.x] = s[0];
}

// ---------------- scan step 2 (merged): offsets + next[] + dinv --------------
__global__ __launch_bounds__(256) void scan_final(const int* __restrict__ counts,
                                                  const int* __restrict__ bsum,
                                                  int* __restrict__ off, int* __restrict__ nxt,
                                                  float* __restrict__ dinv, int n, int nb) {
    __shared__ int s[256];
    __shared__ int sb[128];
    int base = blockIdx.x * 1024;
    int t = threadIdx.x;
    if (t < nb) sb[t] = bsum[t];
    int c[4];
    int sum = 0;
#pragma unroll
    for (int i = 0; i < 4; i++) {
        int idx = base + t * 4 + i;
        c[i] = (idx < n) ? counts[idx] : 0;
        sum += c[i];
    }
    int v0 = sum;
    s[t] = sum;
    __syncthreads();
    for (int o = 1; o < 256; o <<= 1) {
        int v = (t >= o) ? s[t - o] : 0;
        __syncthreads();
        s[t] += v;
        __syncthreads();
    }
    int blockBase = 0;
    for (int j = 0; j < blockIdx.x; j++) blockBase += sb[j];
    int excl = s[t] - v0 + blockBase;
#pragma unroll
    for (int i = 0; i < 4; i++) {
        int idx = base + t * 4 + i;
        if (idx < n) {
            off[idx] = excl;
            nxt[idx] = excl;
            dinv[idx] = rsqrtf((float)(c[i] + 1));  // +1 = self loop
        }
        excl += c[i];
    }
    if (blockIdx.x == gridDim.x - 1 && t == 255) off[n] = excl;  // == E
}

// ---------------- FUSED fill + gemm-half-B -----------------------------------
// fill (latency-bound ~47us alone) + gemmB (tiles [3125,6250), 1024 blocks).
// Interleave b%7: r<2 -> gemm, else fill (R13-proven pattern).
__global__ __launch_bounds__(256) void fillgemmB_kernel(const float* __restrict__ A,
                                                        const ushort16* __restrict__ Wt,
                                                        ushort16* __restrict__ Ch, int n,
                                                        const int* __restrict__ row,
                                                        const int* __restrict__ col,
                                                        int* __restrict__ nxt,
                                                        int* __restrict__ srcArr, int E) {
    const int b = blockIdx.x;
    const int r7 = b % 7;
    const int g7 = b / 7;
    const int t = threadIdx.x;
    if (r7 >= 2) {
        // fill role: 5/7 -> fill block id in [0, 2560)
        int fb = g7 * 5 + (r7 - 2);
        int e = fb * 256 + t;
        if (e < E) {
            int c = col[e], r = row[e];
            int p = atomicAdd(&nxt[c], 1);
            __builtin_nontemporal_store(r, &srcArr[p]);
        }
        return;
    }
    // gemm role: 2/7 -> gemm block id in [0, 1024); 2048 wave-pairs, stride 2048
    int gb = g7 * 2 + r7;
    gemm_body(A, Wt, Ch, n, gb * 2 + ((t >> 6) >> 1), 2048, 3125, 6250, t);
}

// ---------------- gather-propagate over bf16 table (R11 structure) -----------
// H[c] = dinv[c]^2*T[c] + sum_e dinv[c]*dinv[src_e]*T[src_e].
// 4 edge-groups x 16 lanes x 16B, unroll-2. Measured floor ~48us (L2-miss
// traffic at L3 random-access rate; R12's half-table split REGRESSED).
__global__ __launch_bounds__(256) void gather_kernel(const int* __restrict__ off,
                                                     const int* __restrict__ srcArr,
                                                     const float* __restrict__ dinv,
                                                     const ushort16* __restrict__ XWh,
                                                     ushort16* __restrict__ Hh, int n,
                                                     int leaky) {
    int node = blockIdx.x * 4 + (threadIdx.x >> 6);
    if (node >= n) return;
    int lane = threadIdx.x & 63;
    int grp = lane >> 4;
    int l16 = lane & 15;
    float dc = dinv[node];
    const uint4* table = (const uint4*)XWh;

    f32x2 acc[4];
    if (grp == 0) {  // self-loop term
        uint4 v = table[(size_t)node * 16 + l16];
        f32x2 w0 = (f32x2){dc * dc, dc * dc};
        acc[0] = w0 * up2(v.x);
        acc[1] = w0 * up2(v.y);
        acc[2] = w0 * up2(v.z);
        acc[3] = w0 * up2(v.w);
    } else {
#pragma unroll
        for (int j = 0; j < 4; j++) acc[j] = (f32x2){0.f, 0.f};
    }

    int s = off[node], e = off[node + 1];
    int i = s + grp;
    for (; i + 4 < e; i += 8) {
        int r0 = srcArr[i];
        int r1 = srcArr[i + 4];
        uint4 u0 = table[(size_t)r0 * 16 + l16];
        uint4 u1 = table[(size_t)r1 * 16 + l16];
        float f0 = dc * dinv[r0];
        float f1 = dc * dinv[r1];
        f32x2 n0 = (f32x2){f0, f0};
        f32x2 n1 = (f32x2){f1, f1};
        acc[0] += n0 * up2(u0.x);
        acc[1] += n0 * up2(u0.y);
        acc[2] += n0 * up2(u0.z);
        acc[3] += n0 * up2(u0.w);
        acc[0] += n1 * up2(u1.x);
        acc[1] += n1 * up2(u1.y);
        acc[2] += n1 * up2(u1.z);
        acc[3] += n1 * up2(u1.w);
    }
    if (i < e) {
        int r0 = srcArr[i];
        uint4 u0 = table[(size_t)r0 * 16 + l16];
        float f0 = dc * dinv[r0];
        f32x2 n0 = (f32x2){f0, f0};
        acc[0] += n0 * up2(u0.x);
        acc[1] += n0 * up2(u0.y);
        acc[2] += n0 * up2(u0.z);
        acc[3] += n0 * up2(u0.w);
    }

    float b[8] = {acc[0].x, acc[0].y, acc[1].x, acc[1].y,
                  acc[2].x, acc[2].y, acc[3].x, acc[3].y};
#pragma unroll
    for (int j = 0; j < 8; j++) {
        b[j] += __shfl_xor(b[j], 16);
        b[j] += __shfl_xor(b[j], 32);
    }

    if (grp == 0) {
        if (leaky) {
#pragma unroll
            for (int j = 0; j < 8; j++) b[j] = (b[j] >= 0.f) ? b[j] : 0.01f * b[j];
        }
        uint4 o;
        o.x = (uint32)f2bf(b[0]) | ((uint32)f2bf(b[1]) << 16);
        o.y = (uint32)f2bf(b[2]) | ((uint32)f2bf(b[3]) << 16);
        o.z = (uint32)f2bf(b[4]) | ((uint32)f2bf(b[5]) << 16);
        o.w = (uint32)f2bf(b[6]) | ((uint32)f2bf(b[7]) << 16);
        *(uint4*)(Hh + (size_t)node * FEAT + l16 * 8) = o;
    }
}

// ---------------- pool: P[g] += G3[i] for batch[i]==g (sorted) ---------------
// 32 rows/block (R14: 2x parallelism vs 64; atomics 0.8M->1.6M, harmless)
__global__ __launch_bounds__(128) void pool_kernel(const ushort16* __restrict__ H,
                                                   const int* __restrict__ batch,
                                                   float* __restrict__ P, int n) {
    int t = threadIdx.x;  // feature
    int i0 = blockIdx.x * 32;
    if (i0 >= n) return;
    int i1 = min(i0 + 32, n);
    float acc = 0.f;
    int g = batch[i0];
    for (int i = i0; i < i1; i++) {
        int b = batch[i];
        if (b != g) {
            atomicAdd(&P[(size_t)g * FEAT + t], acc);
            acc = 0.f;
            g = b;
        }
        uint32 u = (uint32)(unsigned short)H[(size_t)i * FEAT + t];
        acc += __uint_as_float(u << 16);
    }
    atomicAdd(&P[(size_t)g * FEAT + t], acc);
}

// ---------------- final tiny GEMM: out[g] = P[g] @ W2 (fp32) -----------------
__global__ __launch_bounds__(128) void pgemm_kernel(const float* __restrict__ P,
                                                    const float* __restrict__ W2,
                                                    float* __restrict__ out) {
    __shared__ float sP[FEAT];
    const int g = blockIdx.x;
    const int t = threadIdx.x;
    sP[t] = P[(size_t)g * FEAT + t];
    __syncthreads();
    float o = 0.f;
#pragma unroll 4
    for (int k = 0; k < FEAT; k++) o += sP[k] * W2[(size_t)k * FEAT + t];
    out[(size_t)g * FEAT + t] = o;
}

extern "C" void kernel_launch(void* const* d_in, const int* in_sizes, int n_in,
                              void* d_out, int out_size, void* d_ws, size_t ws_size,
                              hipStream_t stream) {
    const float* x = (const float*)d_in[0];
    const int* ei = (const int*)d_in[1];
    const int* batch = (const int*)d_in[2];
    const float* W0 = (const float*)d_in[3];
    const float* W1 = (const float*)d_in[4];
    const float* W2 = (const float*)d_in[5];
    float* out = (float*)d_out;

    const int N = in_sizes[0] / FEAT;  // 100000
    const int E = in_sizes[1] / 2;     // 640000
    const int G = out_size / FEAT;     // 512

    const int* rowI = ei;
    const int* colI = ei + E;

    char* ws = (char*)d_ws;
    auto take = [&](size_t bytes) {
        char* p = ws;
        ws += (bytes + 15) & ~(size_t)15;
        return p;
    };
    int* counts    = (int*)take((size_t)N * 4);
    int* off       = (int*)take((size_t)(N + 1) * 4);
    int* nxt       = (int*)take((size_t)N * 4);
    float* dinv    = (float*)take((size_t)N * 4);
    int* bsum      = (int*)take(128 * 4);
    int* srcArr    = (int*)take((size_t)E * 4);
    ushort16* W01t = (ushort16*)take((size_t)16384 * 2);
    float* Pbuf    = (float*)take((size_t)G * FEAT * 4);
    ushort16* bufA = (ushort16*)take((size_t)N * FEAT * 2);
    ushort16* bufB = (ushort16*)take((size_t)N * FEAT * 2);

    const int nb = (N + 1023) / 1024;  // 98

    // ---- pre: zero counts + W01 + zero P (one dispatch, no memset) ----
    pre_kernel<<<196, 256, 0, stream>>>(counts, N, W0, W1, W01t, Pbuf);

    // ---- hist (latency) || gemm-half-A (tiles [0,3125)) ----
    histgemmA_kernel<<<128 * 9, 256, 0, stream>>>(colI, counts, E, x, W01t, bufA, N);

    // ---- CSR scan (2 kernels) ----
    scan_part<<<nb, 256, 0, stream>>>(counts, bsum, N);
    scan_final<<<nb, 256, 0, stream>>>(counts, bsum, off, nxt, dinv, N, nb);

    // ---- fill (latency) || gemm-half-B (tiles [3125,6250)) ----
    fillgemmB_kernel<<<512 * 7, 256, 0, stream>>>(x, W01t, bufA, N,
                                                  rowI, colI, nxt, srcArr, E);

    const int gatBlocks = (N + 3) / 4;
    // ---- H3 = leaky(A A Y) ----
    gather_kernel<<<gatBlocks, 256, 0, stream>>>(off, srcArr, dinv, bufA, bufB, N, 0);
    gather_kernel<<<gatBlocks, 256, 0, stream>>>(off, srcArr, dinv, bufB, bufA, N, 1);
    // ---- G3 = A H3 ----
    gather_kernel<<<gatBlocks, 256, 0, stream>>>(off, srcArr, dinv, bufA, bufB, N, 0);
    // ---- out = pool(G3) @ W2 ----
    pool_kernel<<<(N + 31) / 32, 128, 0, stream>>>(bufB, batch, Pbuf, N);
    pgemm_kernel<<<G, 128, 0, stream>>>(Pbuf, W2, out);
}